// Round 1
// baseline (528.175 us; speedup 1.0000x reference)
//
#include <hip/hip_runtime.h>
#include <stdint.h>

// R7: occupancy attack. R6 fixed the spill by going to __launch_bounds__(256,2),
// but that pins residency at 2 blocks/CU: unified-RF usage is 64 AGPR acc +
// 128 arch VGPR = 192/wave -> floor(512/192) = 2 waves/SIMD = 22.6% occupancy.
// Counters say latency-bound (HBM 0.11%, Mfma 10.6%, VALU 18.8%): 2 independent
// blocks/CU cannot cover L2 B-stream latency + 9 barriers/block.
// Change 1: __launch_bounds__(256,3) -> 170-reg budget. Allocator must shed
//   ~22 regs (fewer B-loads in flight) -- acc(64)+operands(~48) fit with slack,
//   so spill risk is low (unlike the 128-budget R3-R5 disaster). 3 blocks/CU.
//   LDS 36.4 KB x 3 = 109 KB < 160 KB, not binding.
// Change 2: pack_weights reads were stride-1KB gathers; remap so reads are
//   v = W[idx] (fully coalesced) and the transpose scatter moves to the
//   store side (fire-and-forget). Shrinks the 64 us pack+gap overhead.
// Everything else identical to R6.

#define NRAYS 4096

typedef unsigned short u16;
typedef __attribute__((ext_vector_type(8))) short short8;
typedef __attribute__((ext_vector_type(4))) float f32x4;

__device__ __forceinline__ u16 f2bf(float f) {
  union { float f; uint32_t i; } v; v.f = f;
  return (u16)((v.i + 0x7FFFu + ((v.i >> 16) & 1u)) >> 16);
}
__device__ __forceinline__ float bf2f(u16 u) {
  union { uint32_t i; float f; } v; v.i = ((uint32_t)u) << 16; return v.f;
}

// ---------------- weight transpose + fp32->bf16 convert into workspace ----------------
// ws (bf16 elems): W2t [256n][256k] @0, W3t [256n][256k] @65536, W4t [128n][256k] @131072
// Reads are coalesced (v = W[idx]); the transpose happens on the store side.
__global__ void pack_weights(const float* __restrict__ W2, const float* __restrict__ W3,
                             const float* __restrict__ W4, u16* __restrict__ ws) {
  int idx = blockIdx.x * 256 + threadIdx.x;   // grid covers exactly 163840
  float v;
  int dst;
  if (idx < 65536) {
    int k = idx >> 8, n = idx & 255;          // W2 row-major [k][n]
    v = W2[idx];
    dst = n * 256 + k;
  } else if (idx < 131072) {
    int o = idx - 65536, k = o >> 8, n = o & 255;
    v = W3[o];
    dst = 65536 + n * 256 + k;
  } else {
    int o = idx - 131072, k = o >> 7, n = o & 127;  // W4 row-major [k][128], k<256 part
    v = W4[o];
    dst = 131072 + n * 256 + k;
  }
  ws[dst] = f2bf(v);
}

#define MFMA __builtin_amdgcn_mfma_f32_16x16x32_bf16

#define ZER4 (f32x4){0.f, 0.f, 0.f, 0.f}

// one K-step (K=32) of the 4-col-tile GEMM: 4 B loads (global), 4 A loads (LDS), 16 MFMA
#define KSTEP4(sq_) do {                                                     \
    const int sq = (sq_);                                                    \
    short8 bv0 = *(const short8*)(bp0 + sq * 8);                             \
    short8 bv1 = *(const short8*)(bp1 + sq * 8);                             \
    short8 bv2 = *(const short8*)(bp2 + sq * 8);                             \
    short8 bv3 = *(const short8*)(bp3 + sq * 8);                             \
    short8 av0 = *(const short8*)(act + m0 * 256 + ((sq ^ (m0 & 31)) << 3)); \
    short8 av1 = *(const short8*)(act + m1 * 256 + ((sq ^ (m1 & 31)) << 3)); \
    short8 av2 = *(const short8*)(act + m2 * 256 + ((sq ^ (m2 & 31)) << 3)); \
    short8 av3 = *(const short8*)(act + m3 * 256 + ((sq ^ (m3 & 31)) << 3)); \
    c00 = MFMA(av0, bv0, c00, 0, 0, 0); c10 = MFMA(av1, bv0, c10, 0, 0, 0);  \
    c20 = MFMA(av2, bv0, c20, 0, 0, 0); c30 = MFMA(av3, bv0, c30, 0, 0, 0);  \
    c01 = MFMA(av0, bv1, c01, 0, 0, 0); c11 = MFMA(av1, bv1, c11, 0, 0, 0);  \
    c21 = MFMA(av2, bv1, c21, 0, 0, 0); c31 = MFMA(av3, bv1, c31, 0, 0, 0);  \
    c02 = MFMA(av0, bv2, c02, 0, 0, 0); c12 = MFMA(av1, bv2, c12, 0, 0, 0);  \
    c22 = MFMA(av2, bv2, c22, 0, 0, 0); c32 = MFMA(av3, bv2, c32, 0, 0, 0);  \
    c03 = MFMA(av0, bv3, c03, 0, 0, 0); c13 = MFMA(av1, bv3, c13, 0, 0, 0);  \
    c23 = MFMA(av2, bv3, c23, 0, 0, 0); c33 = MFMA(av3, bv3, c33, 0, 0, 0);  \
  } while (0)

// one K-step of the 2-col-tile GEMM (layer 4)
#define KSTEP2(sq_) do {                                                     \
    const int sq = (sq_);                                                    \
    short8 bv0 = *(const short8*)(bp0 + sq * 8);                             \
    short8 bv1 = *(const short8*)(bp1 + sq * 8);                             \
    short8 av0 = *(const short8*)(act + m0 * 256 + ((sq ^ (m0 & 31)) << 3)); \
    short8 av1 = *(const short8*)(act + m1 * 256 + ((sq ^ (m1 & 31)) << 3)); \
    short8 av2 = *(const short8*)(act + m2 * 256 + ((sq ^ (m2 & 31)) << 3)); \
    short8 av3 = *(const short8*)(act + m3 * 256 + ((sq ^ (m3 & 31)) << 3)); \
    c00 = MFMA(av0, bv0, c00, 0, 0, 0); c10 = MFMA(av1, bv0, c10, 0, 0, 0);  \
    c20 = MFMA(av2, bv0, c20, 0, 0, 0); c30 = MFMA(av3, bv0, c30, 0, 0, 0);  \
    c01 = MFMA(av0, bv1, c01, 0, 0, 0); c11 = MFMA(av1, bv1, c11, 0, 0, 0);  \
    c21 = MFMA(av2, bv1, c21, 0, 0, 0); c31 = MFMA(av3, bv1, c31, 0, 0, 0);  \
  } while (0)

// store one 16x16 C-tile (named f32x4 CV), row-tile mt, column ng, into swizzled act
#define EPIC(CV, mt, ng, addv) do {                                          \
    int su_ = ((ng) >> 3), so_ = ((ng) & 7);                                 \
    _Pragma("unroll")                                                        \
    for (int r = 0; r < 4; r++) {                                            \
      int mm = (mt) * 16 + quad * 4 + r;                                     \
      act[mm * 256 + ((su_ ^ (mm & 31)) << 3) + so_] =                       \
          f2bf(fmaxf((CV)[r] + (addv), 0.f));                                \
    }                                                                        \
  } while (0)

__global__ void __launch_bounds__(256, 3) nerf_fused(
    const float* __restrict__ rays_o, const float* __restrict__ rays_d,
    const float* __restrict__ t_rand,
    const float* __restrict__ W1, const float* __restrict__ b1,
    const float* __restrict__ b2, const float* __restrict__ b3,
    const float* __restrict__ Wd, const float* __restrict__ bd,
    const float* __restrict__ W4, const float* __restrict__ b4,
    const float* __restrict__ W5, const float* __restrict__ b5,
    const u16* __restrict__ wpack, float* __restrict__ out) {
  __shared__ u16   act[64 * 256];    // 32 KB, XOR-swizzled slots
  __shared__ float zv[64];
  __shared__ float dist[64];
  __shared__ float dens[64];
  __shared__ float rgbL[64 * 4];
  __shared__ float vdirL[4];
  __shared__ float w5L[384];
  __shared__ float b5L[4];

  const int t = threadIdx.x;
  const int lane = t & 63;
  const int wv = t >> 6;        // 0..3
  const int quad = lane >> 4;
  const int l15 = lane & 15;
  const int ray = blockIdx.x;
  const int m0 = l15, m1 = l15 + 16, m2 = l15 + 32, m3 = l15 + 48;

  // ---- setup ----
  if (t < 64) {
    int j = t;
    float fj = (float)j;
    float zj = 0.5f + 2.0f * (fj / 63.0f);
    float lower = (j == 0)  ? zj : 0.5f * (zj + (0.5f + 2.0f * ((fj - 1.0f) / 63.0f)));
    float upper = (j == 63) ? zj : 0.5f * (zj + (0.5f + 2.0f * ((fj + 1.0f) / 63.0f)));
    float tr = t_rand[ray * 64 + j];
    zv[j] = lower + (upper - lower) * tr;
  } else {
    int idx = t - 64;                 // 0..191
    w5L[idx] = W5[idx];
    w5L[idx + 192] = W5[idx + 192];
  }
  if (t < 3) b5L[t] = b5[t];
  if (t == 0) {
    float dx = rays_d[ray * 3 + 0];
    float dy = rays_d[ray * 3 + 1];
    float dz = rays_d[ray * 3 + 2];
    float nrm = sqrtf(dx * dx + dy * dy + dz * dz) + 1e-8f;
    vdirL[0] = dx / nrm; vdirL[1] = dy / nrm; vdirL[2] = dz / nrm;
  }
  __syncthreads();

  if (t < 64) dist[t] = (t < 63) ? (zv[t + 1] - zv[t]) : 1e10f;

  // ---- layer 1: h1 = relu(pts@W1 + b1) -> act (pure vector ops) ----
  {
    int m = t >> 2, p = t & 3;
    float zm = zv[m];
    float px = rays_o[ray * 3 + 0] + rays_d[ray * 3 + 0] * zm;
    float py = rays_o[ray * 3 + 1] + rays_d[ray * 3 + 1] * zm;
    float pz = rays_o[ray * 3 + 2] + rays_d[ray * 3 + 2] * zm;
#pragma unroll
    for (int kk = 0; kk < 64; kk += 8) {
      int k0 = p * 64 + kk;
      f32x4 bva = *(const f32x4*)(b1 + k0);
      f32x4 bvb = *(const f32x4*)(b1 + k0 + 4);
      f32x4 w0a = *(const f32x4*)(W1 + k0);
      f32x4 w0b = *(const f32x4*)(W1 + k0 + 4);
      f32x4 w1a = *(const f32x4*)(W1 + 256 + k0);
      f32x4 w1b = *(const f32x4*)(W1 + 256 + k0 + 4);
      f32x4 w2a = *(const f32x4*)(W1 + 512 + k0);
      f32x4 w2b = *(const f32x4*)(W1 + 512 + k0 + 4);
      f32x4 sa = bva + px * w0a + py * w1a + pz * w2a;
      f32x4 sb = bvb + px * w0b + py * w1b + pz * w2b;
      short8 res;
      res[0] = (short)f2bf(fmaxf(sa[0], 0.f));
      res[1] = (short)f2bf(fmaxf(sa[1], 0.f));
      res[2] = (short)f2bf(fmaxf(sa[2], 0.f));
      res[3] = (short)f2bf(fmaxf(sa[3], 0.f));
      res[4] = (short)f2bf(fmaxf(sb[0], 0.f));
      res[5] = (short)f2bf(fmaxf(sb[1], 0.f));
      res[6] = (short)f2bf(fmaxf(sb[2], 0.f));
      res[7] = (short)f2bf(fmaxf(sb[3], 0.f));
      int u = (k0 >> 3) ^ (m & 31);
      *(short8*)(act + m * 256 + u * 8) = res;
    }
  }
  __syncthreads();

  // ---- layers 2 & 3: h = relu(h@W + b), K=256, N=256, B streamed from L2 ----
#pragma unroll 1
  for (int L = 0; L < 2; L++) {
    const u16* wB = wpack + L * 65536;
    const float* bb = (L == 0) ? b2 : b3;
    const u16* bp0 = wB + (wv * 64 +  0 + l15) * 256;
    const u16* bp1 = wB + (wv * 64 + 16 + l15) * 256;
    const u16* bp2 = wB + (wv * 64 + 32 + l15) * 256;
    const u16* bp3 = wB + (wv * 64 + 48 + l15) * 256;
    f32x4 c00 = ZER4, c01 = ZER4, c02 = ZER4, c03 = ZER4;
    f32x4 c10 = ZER4, c11 = ZER4, c12 = ZER4, c13 = ZER4;
    f32x4 c20 = ZER4, c21 = ZER4, c22 = ZER4, c23 = ZER4;
    f32x4 c30 = ZER4, c31 = ZER4, c32 = ZER4, c33 = ZER4;
#pragma unroll
    for (int kc = 0; kc < 8; kc++) KSTEP4(kc * 4 + quad);
    __syncthreads();               // all act reads done before in-place rewrite
    {
      int ng0 = wv * 64 + l15;
      float bi0 = bb[ng0], bi1 = bb[ng0 + 16], bi2 = bb[ng0 + 32], bi3 = bb[ng0 + 48];
      EPIC(c00, 0, ng0, bi0); EPIC(c10, 1, ng0, bi0);
      EPIC(c20, 2, ng0, bi0); EPIC(c30, 3, ng0, bi0);
      EPIC(c01, 0, ng0 + 16, bi1); EPIC(c11, 1, ng0 + 16, bi1);
      EPIC(c21, 2, ng0 + 16, bi1); EPIC(c31, 3, ng0 + 16, bi1);
      EPIC(c02, 0, ng0 + 32, bi2); EPIC(c12, 1, ng0 + 32, bi2);
      EPIC(c22, 2, ng0 + 32, bi2); EPIC(c32, 3, ng0 + 32, bi2);
      EPIC(c03, 0, ng0 + 48, bi3); EPIC(c13, 1, ng0 + 48, bi3);
      EPIC(c23, 2, ng0 + 48, bi3); EPIC(c33, 3, ng0 + 48, bi3);
    }
    __syncthreads();
  }

  // ---- density: fp32 dot(h3, Wd) ----
  {
    int m = t >> 2, p = t & 3;
    float s = 0.f;
#pragma unroll
    for (int kk = 0; kk < 64; kk += 8) {
      int k0 = p * 64 + kk;
      short8 h = *(const short8*)(act + m * 256 + (((k0 >> 3) ^ (m & 31)) << 3));
      f32x4 wa = *(const f32x4*)(Wd + k0);
      f32x4 wb = *(const f32x4*)(Wd + k0 + 4);
      s += bf2f((u16)h[0]) * wa[0] + bf2f((u16)h[1]) * wa[1]
         + bf2f((u16)h[2]) * wa[2] + bf2f((u16)h[3]) * wa[3]
         + bf2f((u16)h[4]) * wb[0] + bf2f((u16)h[5]) * wb[1]
         + bf2f((u16)h[6]) * wb[2] + bf2f((u16)h[7]) * wb[3];
    }
    s += __shfl_xor(s, 1);
    s += __shfl_xor(s, 2);
    if (p == 0) dens[m] = s + bd[0];
  }

  // ---- layer 4: h4 = relu(h3@W4[:256] + vdir@W4[256:259] + b4), N=128 ----
  {
    const u16* wB = wpack + 131072;
    const u16* bp0 = wB + (wv * 32 +  0 + l15) * 256;
    const u16* bp1 = wB + (wv * 32 + 16 + l15) * 256;
    f32x4 c00 = ZER4, c01 = ZER4;
    f32x4 c10 = ZER4, c11 = ZER4;
    f32x4 c20 = ZER4, c21 = ZER4;
    f32x4 c30 = ZER4, c31 = ZER4;
#pragma unroll
    for (int kc = 0; kc < 8; kc++) KSTEP2(kc * 4 + quad);
    __syncthreads();               // all h3 reads done (incl. density) before rewrite
    {
      float v0 = vdirL[0], v1 = vdirL[1], v2 = vdirL[2];
      int ng0 = wv * 32 + l15;
      float ad0 = b4[ng0] + v0 * W4[32768 + ng0] + v1 * W4[32896 + ng0] + v2 * W4[33024 + ng0];
      int ng1 = ng0 + 16;
      float ad1 = b4[ng1] + v0 * W4[32768 + ng1] + v1 * W4[32896 + ng1] + v2 * W4[33024 + ng1];
      EPIC(c00, 0, ng0, ad0); EPIC(c10, 1, ng0, ad0);
      EPIC(c20, 2, ng0, ad0); EPIC(c30, 3, ng0, ad0);
      EPIC(c01, 0, ng1, ad1); EPIC(c11, 1, ng1, ad1);
      EPIC(c21, 2, ng1, ad1); EPIC(c31, 3, ng1, ad1);
    }
  }
  __syncthreads();

  // ---- rgb = sigmoid(h4@W5 + b5) ----
  {
    int m = t >> 2, p = t & 3;
    float s0 = 0.f, s1 = 0.f, s2 = 0.f;
#pragma unroll
    for (int kk = 0; kk < 32; kk += 8) {
      int k0 = p * 32 + kk;
      short8 h = *(const short8*)(act + m * 256 + (((k0 >> 3) ^ (m & 31)) << 3));
#pragma unroll
      for (int j = 0; j < 8; j++) {
        float hv = bf2f((u16)h[j]);
        int k = k0 + j;
        s0 += hv * w5L[k * 3 + 0];
        s1 += hv * w5L[k * 3 + 1];
        s2 += hv * w5L[k * 3 + 2];
      }
    }
    s0 += __shfl_xor(s0, 1); s0 += __shfl_xor(s0, 2);
    s1 += __shfl_xor(s1, 1); s1 += __shfl_xor(s1, 2);
    s2 += __shfl_xor(s2, 1); s2 += __shfl_xor(s2, 2);
    if (p == 0) {
      rgbL[m * 4 + 0] = 1.f / (1.f + __expf(-(s0 + b5L[0])));
      rgbL[m * 4 + 1] = 1.f / (1.f + __expf(-(s1 + b5L[1])));
      rgbL[m * 4 + 2] = 1.f / (1.f + __expf(-(s2 + b5L[2])));
    }
  }
  __syncthreads();

  // ---- alpha compositing: wave 0 handles the block's single ray ----
  if (t < 64) {
    int j = t;
    float alpha = 1.f - __expf(-fmaxf(dens[j], 0.f) * dist[j]);
    float v = 1.f - alpha + 1e-10f;
    float pscan = v;
#pragma unroll
    for (int d = 1; d < 64; d <<= 1) {
      float o = __shfl_up(pscan, d);
      if (j >= d) pscan *= o;
    }
    float T = __shfl_up(pscan, 1);
    if (j == 0) T = 1.f;
    float w = alpha * T;
    float r0 = w * rgbL[j * 4 + 0];
    float r1 = w * rgbL[j * 4 + 1];
    float r2 = w * rgbL[j * 4 + 2];
    float dp = w * zv[j];
    float ac = w;
#pragma unroll
    for (int d = 32; d; d >>= 1) {
      r0 += __shfl_down(r0, d);
      r1 += __shfl_down(r1, d);
      r2 += __shfl_down(r2, d);
      dp += __shfl_down(dp, d);
      ac += __shfl_down(ac, d);
    }
    if (j == 0) {
      float bg = 1.f - ac;
      out[ray * 3 + 0] = r0 + bg;
      out[ray * 3 + 1] = r1 + bg;
      out[ray * 3 + 2] = r2 + bg;
      out[NRAYS * 3 + ray] = dp;
      out[NRAYS * 4 + ray] = ac;
    }
  }
}

extern "C" void kernel_launch(void* const* d_in, const int* in_sizes, int n_in,
                              void* d_out, int out_size, void* d_ws, size_t ws_size,
                              hipStream_t stream) {
  const float* rays_o = (const float*)d_in[0];
  const float* rays_d = (const float*)d_in[1];
  const float* t_rand = (const float*)d_in[2];
  const float* W1 = (const float*)d_in[3];
  const float* b1 = (const float*)d_in[4];
  const float* W2 = (const float*)d_in[5];
  const float* b2 = (const float*)d_in[6];
  const float* W3 = (const float*)d_in[7];
  const float* b3 = (const float*)d_in[8];
  const float* Wd = (const float*)d_in[9];
  const float* bd = (const float*)d_in[10];
  const float* W4 = (const float*)d_in[11];
  const float* b4 = (const float*)d_in[12];
  const float* W5 = (const float*)d_in[13];
  const float* b5 = (const float*)d_in[14];
  u16* wpack = (u16*)d_ws;
  float* out = (float*)d_out;

  pack_weights<<<640, 256, 0, stream>>>(W2, W3, W4, wpack);
  nerf_fused<<<NRAYS, 256, 0, stream>>>(rays_o, rays_d, t_rand, W1, b1, b2, b3,
                                        Wd, bd, W4, b4, W5, b5, wpack, out);
}

// Round 2
// 461.016 us; speedup vs baseline: 1.1457x; 1.1457x over previous
//
#include <hip/hip_runtime.h>
#include <stdint.h>

// R8: occupancy via acc-split, not allocator pressure. R7 post-mortem: 170-reg
// budget with 16 acc tiles/wave spilled ~450 MB/dispatch (FETCH 158MB, WRITE
// 291MB) -> 459us. The 16-acc structure has a ~190-reg steady state; it can
// only ever run 2 waves/SIMD. Fix the structure:
//   - 512 threads / 8 waves per ray. Each wave: 64 rows x 32 cols for L2/L3
//     (4 row-tiles x 2 col-tiles = 8 acc = 32 VGPRs), 16 cols for L4 (4 acc).
//   - Steady-state reg demand ~115 -> __launch_bounds__(512,4) budget 128,
//     real headroom (R7 had none). 2 blocks/CU x 8 waves = 16 waves/CU =
//     4 waves/SIMD, 2x the concurrency, waves from 2 independent blocks per
//     SIMD cover each other's barrier drains and L2 B-latency.
//   - LDS ~35.6 KB/block, 2 blocks = 71 KB < 160 KB, not binding.
// pack_weights keeps the R7 coalesced-read layout (verified correct).
// Tripwire: if FETCH/WRITE balloon again -> spill -> reduce unroll next.

#define NRAYS 4096

typedef unsigned short u16;
typedef __attribute__((ext_vector_type(8))) short short8;
typedef __attribute__((ext_vector_type(4))) float f32x4;

__device__ __forceinline__ u16 f2bf(float f) {
  union { float f; uint32_t i; } v; v.f = f;
  return (u16)((v.i + 0x7FFFu + ((v.i >> 16) & 1u)) >> 16);
}
__device__ __forceinline__ float bf2f(u16 u) {
  union { uint32_t i; float f; } v; v.i = ((uint32_t)u) << 16; return v.f;
}

// ---------------- weight transpose + fp32->bf16 convert into workspace ----------------
// ws (bf16 elems): W2t [256n][256k] @0, W3t [256n][256k] @65536, W4t [128n][256k] @131072
// Reads are coalesced (v = W[idx]); the transpose happens on the store side.
__global__ void pack_weights(const float* __restrict__ W2, const float* __restrict__ W3,
                             const float* __restrict__ W4, u16* __restrict__ ws) {
  int idx = blockIdx.x * 256 + threadIdx.x;   // grid covers exactly 163840
  float v;
  int dst;
  if (idx < 65536) {
    int k = idx >> 8, n = idx & 255;          // W2 row-major [k][n]
    v = W2[idx];
    dst = n * 256 + k;
  } else if (idx < 131072) {
    int o = idx - 65536, k = o >> 8, n = o & 255;
    v = W3[o];
    dst = 65536 + n * 256 + k;
  } else {
    int o = idx - 131072, k = o >> 7, n = o & 127;  // W4 row-major [k][128], k<256 part
    v = W4[o];
    dst = 131072 + n * 256 + k;
  }
  ws[dst] = f2bf(v);
}

#define MFMA __builtin_amdgcn_mfma_f32_16x16x32_bf16

#define ZER4 (f32x4){0.f, 0.f, 0.f, 0.f}

// one K-step (K=32) of the 2-col-tile GEMM (layers 2/3): 2 B loads, 4 A loads, 8 MFMA
#define KSTEP8(sq_) do {                                                     \
    const int sq = (sq_);                                                    \
    short8 bv0 = *(const short8*)(bp0 + sq * 8);                             \
    short8 bv1 = *(const short8*)(bp1 + sq * 8);                             \
    short8 av0 = *(const short8*)(act + m0 * 256 + ((sq ^ (m0 & 31)) << 3)); \
    short8 av1 = *(const short8*)(act + m1 * 256 + ((sq ^ (m1 & 31)) << 3)); \
    short8 av2 = *(const short8*)(act + m2 * 256 + ((sq ^ (m2 & 31)) << 3)); \
    short8 av3 = *(const short8*)(act + m3 * 256 + ((sq ^ (m3 & 31)) << 3)); \
    c00 = MFMA(av0, bv0, c00, 0, 0, 0); c10 = MFMA(av1, bv0, c10, 0, 0, 0);  \
    c20 = MFMA(av2, bv0, c20, 0, 0, 0); c30 = MFMA(av3, bv0, c30, 0, 0, 0);  \
    c01 = MFMA(av0, bv1, c01, 0, 0, 0); c11 = MFMA(av1, bv1, c11, 0, 0, 0);  \
    c21 = MFMA(av2, bv1, c21, 0, 0, 0); c31 = MFMA(av3, bv1, c31, 0, 0, 0);  \
  } while (0)

// one K-step of the 1-col-tile GEMM (layer 4): 1 B load, 4 A loads, 4 MFMA
#define KSTEP1(sq_) do {                                                     \
    const int sq = (sq_);                                                    \
    short8 bv0 = *(const short8*)(bp0 + sq * 8);                             \
    short8 av0 = *(const short8*)(act + m0 * 256 + ((sq ^ (m0 & 31)) << 3)); \
    short8 av1 = *(const short8*)(act + m1 * 256 + ((sq ^ (m1 & 31)) << 3)); \
    short8 av2 = *(const short8*)(act + m2 * 256 + ((sq ^ (m2 & 31)) << 3)); \
    short8 av3 = *(const short8*)(act + m3 * 256 + ((sq ^ (m3 & 31)) << 3)); \
    c00 = MFMA(av0, bv0, c00, 0, 0, 0); c10 = MFMA(av1, bv0, c10, 0, 0, 0);  \
    c20 = MFMA(av2, bv0, c20, 0, 0, 0); c30 = MFMA(av3, bv0, c30, 0, 0, 0);  \
  } while (0)

// store one 16x16 C-tile (named f32x4 CV), row-tile mt, column ng, into swizzled act
#define EPIC(CV, mt, ng, addv) do {                                          \
    int su_ = ((ng) >> 3), so_ = ((ng) & 7);                                 \
    _Pragma("unroll")                                                        \
    for (int r = 0; r < 4; r++) {                                            \
      int mm = (mt) * 16 + quad * 4 + r;                                     \
      act[mm * 256 + ((su_ ^ (mm & 31)) << 3) + so_] =                       \
          f2bf(fmaxf((CV)[r] + (addv), 0.f));                                \
    }                                                                        \
  } while (0)

__global__ void __launch_bounds__(512, 4) nerf_fused(
    const float* __restrict__ rays_o, const float* __restrict__ rays_d,
    const float* __restrict__ t_rand,
    const float* __restrict__ W1, const float* __restrict__ b1,
    const float* __restrict__ b2, const float* __restrict__ b3,
    const float* __restrict__ Wd, const float* __restrict__ bd,
    const float* __restrict__ W4, const float* __restrict__ b4,
    const float* __restrict__ W5, const float* __restrict__ b5,
    const u16* __restrict__ wpack, float* __restrict__ out) {
  __shared__ u16   act[64 * 256];    // 32 KB, XOR-swizzled slots
  __shared__ float zv[64];
  __shared__ float dist[64];
  __shared__ float dens[64];
  __shared__ float rgbL[64 * 4];
  __shared__ float vdirL[4];
  __shared__ float w5L[384];
  __shared__ float b5L[4];

  const int t = threadIdx.x;
  const int lane = t & 63;
  const int wv = t >> 6;        // 0..7
  const int quad = lane >> 4;
  const int l15 = lane & 15;
  const int ray = blockIdx.x;
  const int m0 = l15, m1 = l15 + 16, m2 = l15 + 32, m3 = l15 + 48;

  // ---- setup ----
  if (t < 64) {
    int j = t;
    float fj = (float)j;
    float zj = 0.5f + 2.0f * (fj / 63.0f);
    float lower = (j == 0)  ? zj : 0.5f * (zj + (0.5f + 2.0f * ((fj - 1.0f) / 63.0f)));
    float upper = (j == 63) ? zj : 0.5f * (zj + (0.5f + 2.0f * ((fj + 1.0f) / 63.0f)));
    float tr = t_rand[ray * 64 + j];
    zv[j] = lower + (upper - lower) * tr;
  } else if (t < 448) {
    w5L[t - 64] = W5[t - 64];       // 384 floats
  }
  if (t < 3) b5L[t] = b5[t];
  if (t == 0) {
    float dx = rays_d[ray * 3 + 0];
    float dy = rays_d[ray * 3 + 1];
    float dz = rays_d[ray * 3 + 2];
    float nrm = sqrtf(dx * dx + dy * dy + dz * dz) + 1e-8f;
    vdirL[0] = dx / nrm; vdirL[1] = dy / nrm; vdirL[2] = dz / nrm;
  }
  __syncthreads();

  if (t < 64) dist[t] = (t < 63) ? (zv[t + 1] - zv[t]) : 1e10f;

  // ---- layer 1: h1 = relu(pts@W1 + b1) -> act (pure vector ops) ----
  // 512 threads: m = t>>3 (row 0..63), p = t&7 owns 32 of the 256 outputs
  {
    int m = t >> 3, p = t & 7;
    float zm = zv[m];
    float px = rays_o[ray * 3 + 0] + rays_d[ray * 3 + 0] * zm;
    float py = rays_o[ray * 3 + 1] + rays_d[ray * 3 + 1] * zm;
    float pz = rays_o[ray * 3 + 2] + rays_d[ray * 3 + 2] * zm;
#pragma unroll
    for (int kk = 0; kk < 32; kk += 8) {
      int k0 = p * 32 + kk;
      f32x4 bva = *(const f32x4*)(b1 + k0);
      f32x4 bvb = *(const f32x4*)(b1 + k0 + 4);
      f32x4 w0a = *(const f32x4*)(W1 + k0);
      f32x4 w0b = *(const f32x4*)(W1 + k0 + 4);
      f32x4 w1a = *(const f32x4*)(W1 + 256 + k0);
      f32x4 w1b = *(const f32x4*)(W1 + 256 + k0 + 4);
      f32x4 w2a = *(const f32x4*)(W1 + 512 + k0);
      f32x4 w2b = *(const f32x4*)(W1 + 512 + k0 + 4);
      f32x4 sa = bva + px * w0a + py * w1a + pz * w2a;
      f32x4 sb = bvb + px * w0b + py * w1b + pz * w2b;
      short8 res;
      res[0] = (short)f2bf(fmaxf(sa[0], 0.f));
      res[1] = (short)f2bf(fmaxf(sa[1], 0.f));
      res[2] = (short)f2bf(fmaxf(sa[2], 0.f));
      res[3] = (short)f2bf(fmaxf(sa[3], 0.f));
      res[4] = (short)f2bf(fmaxf(sb[0], 0.f));
      res[5] = (short)f2bf(fmaxf(sb[1], 0.f));
      res[6] = (short)f2bf(fmaxf(sb[2], 0.f));
      res[7] = (short)f2bf(fmaxf(sb[3], 0.f));
      int u = (k0 >> 3) ^ (m & 31);
      *(short8*)(act + m * 256 + u * 8) = res;
    }
  }
  __syncthreads();

  // ---- layers 2 & 3: h = relu(h@W + b), K=256, N=256 ----
  // 8 waves: wave wv owns 32 columns [wv*32, wv*32+32): 8 acc tiles/wave
#pragma unroll 1
  for (int L = 0; L < 2; L++) {
    const u16* wB = wpack + L * 65536;
    const float* bb = (L == 0) ? b2 : b3;
    const u16* bp0 = wB + (wv * 32 +  0 + l15) * 256;
    const u16* bp1 = wB + (wv * 32 + 16 + l15) * 256;
    f32x4 c00 = ZER4, c01 = ZER4;
    f32x4 c10 = ZER4, c11 = ZER4;
    f32x4 c20 = ZER4, c21 = ZER4;
    f32x4 c30 = ZER4, c31 = ZER4;
#pragma unroll
    for (int kc = 0; kc < 8; kc++) KSTEP8(kc * 4 + quad);
    __syncthreads();               // all act reads done before in-place rewrite
    {
      int ng0 = wv * 32 + l15;
      float bi0 = bb[ng0], bi1 = bb[ng0 + 16];
      EPIC(c00, 0, ng0, bi0); EPIC(c10, 1, ng0, bi0);
      EPIC(c20, 2, ng0, bi0); EPIC(c30, 3, ng0, bi0);
      EPIC(c01, 0, ng0 + 16, bi1); EPIC(c11, 1, ng0 + 16, bi1);
      EPIC(c21, 2, ng0 + 16, bi1); EPIC(c31, 3, ng0 + 16, bi1);
    }
    __syncthreads();
  }

  // ---- density: fp32 dot(h3, Wd) ----
  // m = t>>3 (row), p = t&7 owns 32 of 256 k's; reduce over 8 lanes
  {
    int m = t >> 3, p = t & 7;
    float s = 0.f;
#pragma unroll
    for (int kk = 0; kk < 32; kk += 8) {
      int k0 = p * 32 + kk;
      short8 h = *(const short8*)(act + m * 256 + (((k0 >> 3) ^ (m & 31)) << 3));
      f32x4 wa = *(const f32x4*)(Wd + k0);
      f32x4 wb = *(const f32x4*)(Wd + k0 + 4);
      s += bf2f((u16)h[0]) * wa[0] + bf2f((u16)h[1]) * wa[1]
         + bf2f((u16)h[2]) * wa[2] + bf2f((u16)h[3]) * wa[3]
         + bf2f((u16)h[4]) * wb[0] + bf2f((u16)h[5]) * wb[1]
         + bf2f((u16)h[6]) * wb[2] + bf2f((u16)h[7]) * wb[3];
    }
    s += __shfl_xor(s, 1);
    s += __shfl_xor(s, 2);
    s += __shfl_xor(s, 4);
    if (p == 0) dens[m] = s + bd[0];
  }

  // ---- layer 4: h4 = relu(h3@W4[:256] + vdir@W4[256:259] + b4), N=128 ----
  // 8 waves: wave wv owns 16 columns: 4 acc tiles/wave
  {
    const u16* wB = wpack + 131072;
    const u16* bp0 = wB + (wv * 16 + l15) * 256;
    f32x4 c00 = ZER4;
    f32x4 c10 = ZER4;
    f32x4 c20 = ZER4;
    f32x4 c30 = ZER4;
#pragma unroll
    for (int kc = 0; kc < 8; kc++) KSTEP1(kc * 4 + quad);
    __syncthreads();               // all h3 reads done (incl. density) before rewrite
    {
      float v0 = vdirL[0], v1 = vdirL[1], v2 = vdirL[2];
      int ng0 = wv * 16 + l15;
      float ad0 = b4[ng0] + v0 * W4[32768 + ng0] + v1 * W4[32896 + ng0] + v2 * W4[33024 + ng0];
      EPIC(c00, 0, ng0, ad0); EPIC(c10, 1, ng0, ad0);
      EPIC(c20, 2, ng0, ad0); EPIC(c30, 3, ng0, ad0);
    }
  }
  __syncthreads();

  // ---- rgb = sigmoid(h4@W5 + b5) ----
  // m = t>>3 (row), p = t&7 owns 16 of 128 k's; reduce over 8 lanes
  {
    int m = t >> 3, p = t & 7;
    float s0 = 0.f, s1 = 0.f, s2 = 0.f;
#pragma unroll
    for (int kk = 0; kk < 16; kk += 8) {
      int k0 = p * 16 + kk;
      short8 h = *(const short8*)(act + m * 256 + (((k0 >> 3) ^ (m & 31)) << 3));
#pragma unroll
      for (int j = 0; j < 8; j++) {
        float hv = bf2f((u16)h[j]);
        int k = k0 + j;
        s0 += hv * w5L[k * 3 + 0];
        s1 += hv * w5L[k * 3 + 1];
        s2 += hv * w5L[k * 3 + 2];
      }
    }
    s0 += __shfl_xor(s0, 1); s0 += __shfl_xor(s0, 2); s0 += __shfl_xor(s0, 4);
    s1 += __shfl_xor(s1, 1); s1 += __shfl_xor(s1, 2); s1 += __shfl_xor(s1, 4);
    s2 += __shfl_xor(s2, 1); s2 += __shfl_xor(s2, 2); s2 += __shfl_xor(s2, 4);
    if (p == 0) {
      rgbL[m * 4 + 0] = 1.f / (1.f + __expf(-(s0 + b5L[0])));
      rgbL[m * 4 + 1] = 1.f / (1.f + __expf(-(s1 + b5L[1])));
      rgbL[m * 4 + 2] = 1.f / (1.f + __expf(-(s2 + b5L[2])));
    }
  }
  __syncthreads();

  // ---- alpha compositing: wave 0 handles the block's single ray ----
  if (t < 64) {
    int j = t;
    float alpha = 1.f - __expf(-fmaxf(dens[j], 0.f) * dist[j]);
    float v = 1.f - alpha + 1e-10f;
    float pscan = v;
#pragma unroll
    for (int d = 1; d < 64; d <<= 1) {
      float o = __shfl_up(pscan, d);
      if (j >= d) pscan *= o;
    }
    float T = __shfl_up(pscan, 1);
    if (j == 0) T = 1.f;
    float w = alpha * T;
    float r0 = w * rgbL[j * 4 + 0];
    float r1 = w * rgbL[j * 4 + 1];
    float r2 = w * rgbL[j * 4 + 2];
    float dp = w * zv[j];
    float ac = w;
#pragma unroll
    for (int d = 32; d; d >>= 1) {
      r0 += __shfl_down(r0, d);
      r1 += __shfl_down(r1, d);
      r2 += __shfl_down(r2, d);
      dp += __shfl_down(dp, d);
      ac += __shfl_down(ac, d);
    }
    if (j == 0) {
      float bg = 1.f - ac;
      out[ray * 3 + 0] = r0 + bg;
      out[ray * 3 + 1] = r1 + bg;
      out[ray * 3 + 2] = r2 + bg;
      out[NRAYS * 3 + ray] = dp;
      out[NRAYS * 4 + ray] = ac;
    }
  }
}

extern "C" void kernel_launch(void* const* d_in, const int* in_sizes, int n_in,
                              void* d_out, int out_size, void* d_ws, size_t ws_size,
                              hipStream_t stream) {
  const float* rays_o = (const float*)d_in[0];
  const float* rays_d = (const float*)d_in[1];
  const float* t_rand = (const float*)d_in[2];
  const float* W1 = (const float*)d_in[3];
  const float* b1 = (const float*)d_in[4];
  const float* W2 = (const float*)d_in[5];
  const float* b2 = (const float*)d_in[6];
  const float* W3 = (const float*)d_in[7];
  const float* b3 = (const float*)d_in[8];
  const float* Wd = (const float*)d_in[9];
  const float* bd = (const float*)d_in[10];
  const float* W4 = (const float*)d_in[11];
  const float* b4 = (const float*)d_in[12];
  const float* W5 = (const float*)d_in[13];
  const float* b5 = (const float*)d_in[14];
  u16* wpack = (u16*)d_ws;
  float* out = (float*)d_out;

  pack_weights<<<640, 256, 0, stream>>>(W2, W3, W4, wpack);
  nerf_fused<<<NRAYS, 512, 0, stream>>>(rays_o, rays_d, t_rand, W1, b1, b2, b3,
                                        Wd, bd, W4, b4, W5, b5, wpack, out);
}

// Round 3
// 400.409 us; speedup vs baseline: 1.3191x; 1.1514x over previous
//
#include <hip/hip_runtime.h>
#include <stdint.h>

// R9: cap the live set by construction. R7/R8 post-mortem: the spill was never
// about acc count -- the fully-unrolled K-loops hoist ALL B-loads (16 short8 =
// 64 regs) + A + acc + addr ~= 190 live regs, so any budget < 190 spills
// (consistent across (256,2)=OK, (256,3)=spill, (512,4)=spill).
// Changes vs R8 (same 512-thread / 8-wave / 8-acc structure):
//   1. K-loops are '#pragma unroll 1' with explicit depth-1 B-prefetch:
//      live ~= acc(32)+pbuf(8)+cur(8)+A(16)+addr(25) ~= 90 < 128 budget.
//   2. L1 loop also unroll-1 (R8 hoisted 32 f32x4 there = second spill source).
//   3. f2bf (4 VALU ops) -> v_cvt_pk_bf16_f32 (1 op / 2 values, same RNE,
//      bit-identical) in L1 + EPIC epilogues: VALUBusy was 2x MfmaUtil.
// Tripwire: FETCH/WRITE must return to ~3MB/~0.5MB. If not, unroll theory is
// wrong -> revert to R6 structure + 2 rays/block next.

#define NRAYS 4096

typedef unsigned short u16;
typedef __attribute__((ext_vector_type(8))) short short8;
typedef __attribute__((ext_vector_type(4))) float f32x4;
typedef __attribute__((ext_vector_type(4))) unsigned int uint32x4;

__device__ __forceinline__ u16 f2bf(float f) {
  union { float f; uint32_t i; } v; v.f = f;
  return (u16)((v.i + 0x7FFFu + ((v.i >> 16) & 1u)) >> 16);
}
__device__ __forceinline__ float bf2f(u16 u) {
  union { uint32_t i; float f; } v; v.i = ((uint32_t)u) << 16; return v.f;
}
// packed fp32->bf16 (RNE), lo -> bits 15:0, hi -> bits 31:16
__device__ __forceinline__ uint32_t cvtpk(float lo, float hi) {
  uint32_t r;
  asm("v_cvt_pk_bf16_f32 %0, %1, %2" : "=v"(r) : "v"(lo), "v"(hi));
  return r;
}

// ---------------- weight transpose + fp32->bf16 convert into workspace ----------------
// ws (bf16 elems): W2t [256n][256k] @0, W3t [256n][256k] @65536, W4t [128n][256k] @131072
__global__ void pack_weights(const float* __restrict__ W2, const float* __restrict__ W3,
                             const float* __restrict__ W4, u16* __restrict__ ws) {
  int idx = blockIdx.x * 256 + threadIdx.x;   // grid covers exactly 163840
  float v;
  int dst;
  if (idx < 65536) {
    int k = idx >> 8, n = idx & 255;          // W2 row-major [k][n]
    v = W2[idx];
    dst = n * 256 + k;
  } else if (idx < 131072) {
    int o = idx - 65536, k = o >> 8, n = o & 255;
    v = W3[o];
    dst = 65536 + n * 256 + k;
  } else {
    int o = idx - 131072, k = o >> 7, n = o & 127;  // W4 row-major [k][128]
    v = W4[o];
    dst = 131072 + n * 256 + k;
  }
  ws[dst] = f2bf(v);
}

#define MFMA __builtin_amdgcn_mfma_f32_16x16x32_bf16
#define ZER4 (f32x4){0.f, 0.f, 0.f, 0.f}

// store one 16x16 C-tile (f32x4 CV), row-tile mt, column ng, into swizzled act
// (packed bf16 convert: 2 x v_cvt_pk_bf16_f32 instead of 4 x 4-op f2bf)
#define EPIC(CV, mt, ng, addv) do {                                          \
    int su_ = ((ng) >> 3), so_ = ((ng) & 7);                                 \
    float f0_ = fmaxf((CV)[0] + (addv), 0.f);                                \
    float f1_ = fmaxf((CV)[1] + (addv), 0.f);                                \
    float f2_ = fmaxf((CV)[2] + (addv), 0.f);                                \
    float f3_ = fmaxf((CV)[3] + (addv), 0.f);                                \
    uint32_t p01_ = cvtpk(f0_, f1_), p23_ = cvtpk(f2_, f3_);                 \
    int mmb_ = (mt) * 16 + quad * 4;                                         \
    act[(mmb_ + 0) * 256 + ((su_ ^ ((mmb_ + 0) & 31)) << 3) + so_] = (u16)p01_;         \
    act[(mmb_ + 1) * 256 + ((su_ ^ ((mmb_ + 1) & 31)) << 3) + so_] = (u16)(p01_ >> 16); \
    act[(mmb_ + 2) * 256 + ((su_ ^ ((mmb_ + 2) & 31)) << 3) + so_] = (u16)p23_;         \
    act[(mmb_ + 3) * 256 + ((su_ ^ ((mmb_ + 3) & 31)) << 3) + so_] = (u16)(p23_ >> 16); \
  } while (0)

__global__ void __launch_bounds__(512, 4) nerf_fused(
    const float* __restrict__ rays_o, const float* __restrict__ rays_d,
    const float* __restrict__ t_rand,
    const float* __restrict__ W1, const float* __restrict__ b1,
    const float* __restrict__ b2, const float* __restrict__ b3,
    const float* __restrict__ Wd, const float* __restrict__ bd,
    const float* __restrict__ W4, const float* __restrict__ b4,
    const float* __restrict__ W5, const float* __restrict__ b5,
    const u16* __restrict__ wpack, float* __restrict__ out) {
  __shared__ u16   act[64 * 256];    // 32 KB, XOR-swizzled slots
  __shared__ float zv[64];
  __shared__ float dist[64];
  __shared__ float dens[64];
  __shared__ float rgbL[64 * 4];
  __shared__ float vdirL[4];
  __shared__ float w5L[384];
  __shared__ float b5L[4];

  const int t = threadIdx.x;
  const int lane = t & 63;
  const int wv = t >> 6;        // 0..7
  const int quad = lane >> 4;
  const int l15 = lane & 15;
  const int ray = blockIdx.x;
  const int m0 = l15, m1 = l15 + 16, m2 = l15 + 32, m3 = l15 + 48;

  // ---- setup ----
  if (t < 64) {
    int j = t;
    float fj = (float)j;
    float zj = 0.5f + 2.0f * (fj / 63.0f);
    float lower = (j == 0)  ? zj : 0.5f * (zj + (0.5f + 2.0f * ((fj - 1.0f) / 63.0f)));
    float upper = (j == 63) ? zj : 0.5f * (zj + (0.5f + 2.0f * ((fj + 1.0f) / 63.0f)));
    float tr = t_rand[ray * 64 + j];
    zv[j] = lower + (upper - lower) * tr;
  } else if (t < 448) {
    w5L[t - 64] = W5[t - 64];       // 384 floats
  }
  if (t < 3) b5L[t] = b5[t];
  if (t == 0) {
    float dx = rays_d[ray * 3 + 0];
    float dy = rays_d[ray * 3 + 1];
    float dz = rays_d[ray * 3 + 2];
    float nrm = sqrtf(dx * dx + dy * dy + dz * dz) + 1e-8f;
    vdirL[0] = dx / nrm; vdirL[1] = dy / nrm; vdirL[2] = dz / nrm;
  }
  __syncthreads();

  if (t < 64) dist[t] = (t < 63) ? (zv[t + 1] - zv[t]) : 1e10f;

  // ---- layer 1: h1 = relu(pts@W1 + b1) -> act ----
  // m = t>>3 (row 0..63), p = t&7 owns 32 of the 256 outputs. unroll 1: bounded liveness.
  {
    int m = t >> 3, p = t & 7;
    float zm = zv[m];
    float px = rays_o[ray * 3 + 0] + rays_d[ray * 3 + 0] * zm;
    float py = rays_o[ray * 3 + 1] + rays_d[ray * 3 + 1] * zm;
    float pz = rays_o[ray * 3 + 2] + rays_d[ray * 3 + 2] * zm;
#pragma unroll 1
    for (int kk = 0; kk < 32; kk += 8) {
      int k0 = p * 32 + kk;
      f32x4 bva = *(const f32x4*)(b1 + k0);
      f32x4 bvb = *(const f32x4*)(b1 + k0 + 4);
      f32x4 w0a = *(const f32x4*)(W1 + k0);
      f32x4 w0b = *(const f32x4*)(W1 + k0 + 4);
      f32x4 w1a = *(const f32x4*)(W1 + 256 + k0);
      f32x4 w1b = *(const f32x4*)(W1 + 256 + k0 + 4);
      f32x4 w2a = *(const f32x4*)(W1 + 512 + k0);
      f32x4 w2b = *(const f32x4*)(W1 + 512 + k0 + 4);
      f32x4 sa = bva + px * w0a + py * w1a + pz * w2a;
      f32x4 sb = bvb + px * w0b + py * w1b + pz * w2b;
      uint32x4 pk;
      pk[0] = cvtpk(fmaxf(sa[0], 0.f), fmaxf(sa[1], 0.f));
      pk[1] = cvtpk(fmaxf(sa[2], 0.f), fmaxf(sa[3], 0.f));
      pk[2] = cvtpk(fmaxf(sb[0], 0.f), fmaxf(sb[1], 0.f));
      pk[3] = cvtpk(fmaxf(sb[2], 0.f), fmaxf(sb[3], 0.f));
      int u = (k0 >> 3) ^ (m & 31);
      *(uint32x4*)(act + m * 256 + u * 8) = pk;
    }
  }
  __syncthreads();

  // ---- layers 2 & 3: h = relu(h@W + b), K=256, N=256 ----
  // 8 waves, wave owns 32 cols: 8 acc. unroll-1 K-loop + depth-1 B prefetch.
#pragma unroll 1
  for (int L = 0; L < 2; L++) {
    const u16* wB = wpack + L * 65536;
    const float* bb = (L == 0) ? b2 : b3;
    const u16* bp0 = wB + (wv * 32 +  0 + l15) * 256;
    const u16* bp1 = wB + (wv * 32 + 16 + l15) * 256;
    f32x4 c00 = ZER4, c01 = ZER4;
    f32x4 c10 = ZER4, c11 = ZER4;
    f32x4 c20 = ZER4, c21 = ZER4;
    f32x4 c30 = ZER4, c31 = ZER4;
    short8 pb0 = *(const short8*)(bp0 + quad * 8);
    short8 pb1 = *(const short8*)(bp1 + quad * 8);
#pragma unroll 1
    for (int kc = 0; kc < 8; kc++) {
      short8 b0 = pb0, b1v = pb1;
      if (kc < 7) {
        int nq = (kc + 1) * 4 + quad;
        pb0 = *(const short8*)(bp0 + nq * 8);
        pb1 = *(const short8*)(bp1 + nq * 8);
      }
      int sq = kc * 4 + quad;
      int x0 = (sq ^ l15) << 3;               // m0&31 == m2&31 == l15
      int x1 = (sq ^ (l15 + 16)) << 3;        // m1&31 == m3&31 == l15+16
      short8 av0 = *(const short8*)(act + m0 * 256 + x0);
      short8 av1 = *(const short8*)(act + m1 * 256 + x1);
      short8 av2 = *(const short8*)(act + m2 * 256 + x0);
      short8 av3 = *(const short8*)(act + m3 * 256 + x1);
      c00 = MFMA(av0, b0, c00, 0, 0, 0); c10 = MFMA(av1, b0, c10, 0, 0, 0);
      c20 = MFMA(av2, b0, c20, 0, 0, 0); c30 = MFMA(av3, b0, c30, 0, 0, 0);
      c01 = MFMA(av0, b1v, c01, 0, 0, 0); c11 = MFMA(av1, b1v, c11, 0, 0, 0);
      c21 = MFMA(av2, b1v, c21, 0, 0, 0); c31 = MFMA(av3, b1v, c31, 0, 0, 0);
    }
    __syncthreads();               // all act reads done before in-place rewrite
    {
      int ng0 = wv * 32 + l15;
      float bi0 = bb[ng0], bi1 = bb[ng0 + 16];
      EPIC(c00, 0, ng0, bi0); EPIC(c10, 1, ng0, bi0);
      EPIC(c20, 2, ng0, bi0); EPIC(c30, 3, ng0, bi0);
      EPIC(c01, 0, ng0 + 16, bi1); EPIC(c11, 1, ng0 + 16, bi1);
      EPIC(c21, 2, ng0 + 16, bi1); EPIC(c31, 3, ng0 + 16, bi1);
    }
    __syncthreads();
  }

  // ---- density: fp32 dot(h3, Wd) ----
  {
    int m = t >> 3, p = t & 7;
    float s = 0.f;
#pragma unroll
    for (int kk = 0; kk < 32; kk += 8) {
      int k0 = p * 32 + kk;
      short8 h = *(const short8*)(act + m * 256 + (((k0 >> 3) ^ (m & 31)) << 3));
      f32x4 wa = *(const f32x4*)(Wd + k0);
      f32x4 wb = *(const f32x4*)(Wd + k0 + 4);
      s += bf2f((u16)h[0]) * wa[0] + bf2f((u16)h[1]) * wa[1]
         + bf2f((u16)h[2]) * wa[2] + bf2f((u16)h[3]) * wa[3]
         + bf2f((u16)h[4]) * wb[0] + bf2f((u16)h[5]) * wb[1]
         + bf2f((u16)h[6]) * wb[2] + bf2f((u16)h[7]) * wb[3];
    }
    s += __shfl_xor(s, 1);
    s += __shfl_xor(s, 2);
    s += __shfl_xor(s, 4);
    if (p == 0) dens[m] = s + bd[0];
  }

  // ---- layer 4: h4 = relu(h3@W4[:256] + vdir@W4[256:259] + b4), N=128 ----
  {
    const u16* wB = wpack + 131072;
    const u16* bp0 = wB + (wv * 16 + l15) * 256;
    f32x4 c00 = ZER4;
    f32x4 c10 = ZER4;
    f32x4 c20 = ZER4;
    f32x4 c30 = ZER4;
    short8 pb0 = *(const short8*)(bp0 + quad * 8);
#pragma unroll 1
    for (int kc = 0; kc < 8; kc++) {
      short8 b0 = pb0;
      if (kc < 7) {
        int nq = (kc + 1) * 4 + quad;
        pb0 = *(const short8*)(bp0 + nq * 8);
      }
      int sq = kc * 4 + quad;
      int x0 = (sq ^ l15) << 3;
      int x1 = (sq ^ (l15 + 16)) << 3;
      short8 av0 = *(const short8*)(act + m0 * 256 + x0);
      short8 av1 = *(const short8*)(act + m1 * 256 + x1);
      short8 av2 = *(const short8*)(act + m2 * 256 + x0);
      short8 av3 = *(const short8*)(act + m3 * 256 + x1);
      c00 = MFMA(av0, b0, c00, 0, 0, 0); c10 = MFMA(av1, b0, c10, 0, 0, 0);
      c20 = MFMA(av2, b0, c20, 0, 0, 0); c30 = MFMA(av3, b0, c30, 0, 0, 0);
    }
    __syncthreads();               // all h3 reads done (incl. density) before rewrite
    {
      float v0 = vdirL[0], v1 = vdirL[1], v2 = vdirL[2];
      int ng0 = wv * 16 + l15;
      float ad0 = b4[ng0] + v0 * W4[32768 + ng0] + v1 * W4[32896 + ng0] + v2 * W4[33024 + ng0];
      EPIC(c00, 0, ng0, ad0); EPIC(c10, 1, ng0, ad0);
      EPIC(c20, 2, ng0, ad0); EPIC(c30, 3, ng0, ad0);
    }
  }
  __syncthreads();

  // ---- rgb = sigmoid(h4@W5 + b5) ----
  {
    int m = t >> 3, p = t & 7;
    float s0 = 0.f, s1 = 0.f, s2 = 0.f;
#pragma unroll
    for (int kk = 0; kk < 16; kk += 8) {
      int k0 = p * 16 + kk;
      short8 h = *(const short8*)(act + m * 256 + (((k0 >> 3) ^ (m & 31)) << 3));
#pragma unroll
      for (int j = 0; j < 8; j++) {
        float hv = bf2f((u16)h[j]);
        int k = k0 + j;
        s0 += hv * w5L[k * 3 + 0];
        s1 += hv * w5L[k * 3 + 1];
        s2 += hv * w5L[k * 3 + 2];
      }
    }
    s0 += __shfl_xor(s0, 1); s0 += __shfl_xor(s0, 2); s0 += __shfl_xor(s0, 4);
    s1 += __shfl_xor(s1, 1); s1 += __shfl_xor(s1, 2); s1 += __shfl_xor(s1, 4);
    s2 += __shfl_xor(s2, 1); s2 += __shfl_xor(s2, 2); s2 += __shfl_xor(s2, 4);
    if (p == 0) {
      rgbL[m * 4 + 0] = 1.f / (1.f + __expf(-(s0 + b5L[0])));
      rgbL[m * 4 + 1] = 1.f / (1.f + __expf(-(s1 + b5L[1])));
      rgbL[m * 4 + 2] = 1.f / (1.f + __expf(-(s2 + b5L[2])));
    }
  }
  __syncthreads();

  // ---- alpha compositing: wave 0 handles the block's single ray ----
  if (t < 64) {
    int j = t;
    float alpha = 1.f - __expf(-fmaxf(dens[j], 0.f) * dist[j]);
    float v = 1.f - alpha + 1e-10f;
    float pscan = v;
#pragma unroll
    for (int d = 1; d < 64; d <<= 1) {
      float o = __shfl_up(pscan, d);
      if (j >= d) pscan *= o;
    }
    float T = __shfl_up(pscan, 1);
    if (j == 0) T = 1.f;
    float w = alpha * T;
    float r0 = w * rgbL[j * 4 + 0];
    float r1 = w * rgbL[j * 4 + 1];
    float r2 = w * rgbL[j * 4 + 2];
    float dp = w * zv[j];
    float ac = w;
#pragma unroll
    for (int d = 32; d; d >>= 1) {
      r0 += __shfl_down(r0, d);
      r1 += __shfl_down(r1, d);
      r2 += __shfl_down(r2, d);
      dp += __shfl_down(dp, d);
      ac += __shfl_down(ac, d);
    }
    if (j == 0) {
      float bg = 1.f - ac;
      out[ray * 3 + 0] = r0 + bg;
      out[ray * 3 + 1] = r1 + bg;
      out[ray * 3 + 2] = r2 + bg;
      out[NRAYS * 3 + ray] = dp;
      out[NRAYS * 4 + ray] = ac;
    }
  }
}

extern "C" void kernel_launch(void* const* d_in, const int* in_sizes, int n_in,
                              void* d_out, int out_size, void* d_ws, size_t ws_size,
                              hipStream_t stream) {
  const float* rays_o = (const float*)d_in[0];
  const float* rays_d = (const float*)d_in[1];
  const float* t_rand = (const float*)d_in[2];
  const float* W1 = (const float*)d_in[3];
  const float* b1 = (const float*)d_in[4];
  const float* W2 = (const float*)d_in[5];
  const float* b2 = (const float*)d_in[6];
  const float* W3 = (const float*)d_in[7];
  const float* b3 = (const float*)d_in[8];
  const float* Wd = (const float*)d_in[9];
  const float* bd = (const float*)d_in[10];
  const float* W4 = (const float*)d_in[11];
  const float* b4 = (const float*)d_in[12];
  const float* W5 = (const float*)d_in[13];
  const float* b5 = (const float*)d_in[14];
  u16* wpack = (u16*)d_ws;
  float* out = (float*)d_out;

  pack_weights<<<640, 256, 0, stream>>>(W2, W3, W4, wpack);
  nerf_fused<<<NRAYS, 512, 0, stream>>>(rays_o, rays_d, t_rand, W1, b1, b2, b3,
                                        Wd, bd, W4, b4, W5, b5, wpack, out);
}